// Round 9
// baseline (164.010 us; speedup 1.0000x reference)
//
#include <hip/hip_runtime.h>

// SPN left-to-right propagation — SINGLE WAVE per plane, zero barriers.
//
// h[:,:,i,t] = (1-g1-g2-g3)*x[...,i,t] + g1*h[i-1,t-1] + g2*h[i,t-1] + g3*h[i+1,t-1]
// Gates: if |G1|+|G2|+|G3| >= 1, divide by the sum (EPS branch dead).
//
// Evidence-driven design (r1..r8):
//  * r8: halo coefficients through LDS = 4x redundant reads -> DS-pipe bound
//    (~976 cy/ITER) + 5.1M bank conflicts (b128 lane-grouping is stride-8:
//    rows 8 apart at dword-stride 20 alias, 160 % 32 == 0). Halo abandoned.
//  * r4/r6: lane-private 16B VMEM granularity = request-rate poison.
//    Loads here are 32B-row-pair contiguous per instruction, single-touch.
//  * r3: global_load_lds forces vmcnt(0) drains before ds_reads. Plain
//    loads + ds_write get precise per-register counted waits instead.
//  * r5: >= 256 live VGPRs spills. Staging capped at 128 (per-array stagger).
//
// Structure: grid=256 planes, block=64 = ONE wave.
//  - Lane l owns rows {l, 64+l, 128+l, 192+l} (4 stripes). h-exchange is
//    8 shfl/col + 6 boundary readlane-broadcasts. No LDS for h, no barrier.
//  - Per 8-col group: wave loads 4 arrays coalesced (lane -> f4 (l&1) of row
//    32j+(l>>1); 32 instrs of 64x16B), ds_writes into buf[(g+1)&1], lane
//    reads its 4 stripes per col. Single wave => DS pipe is in-order =>
//    double-buffered LDS needs NO sync whatsoever.
//  - LDS layout: dword = buf*8192 + a*2048 + r*8 + (c ^ ((r>>1)&7)).
//    XOR swizzle gives exactly 2 lanes/bank (free) on both the write
//    pattern (key=(l>>2)&7) and the strided read pattern (key=(l>>1)&7),
//    independent of HW lane-grouping. 2 bufs x 4 arrays x 256 x 8 = 64KB.
//  - Stores: 2 adjacent f4/row/group from out-accum regs (32B bursts).

#define SETEL(v, k, val)                                                     \
    do {                                                                     \
        if ((k) == 0) (v).x = (val);                                         \
        else if ((k) == 1) (v).y = (val);                                    \
        else if ((k) == 2) (v).z = (val);                                    \
        else (v).w = (val);                                                  \
    } while (0)

#define FENCE() __builtin_amdgcn_sched_barrier(0)

extern "C" __global__ void __launch_bounds__(64, 1)
spn_wave_x(const float* __restrict__ xg, const float* __restrict__ g1g,
           const float* __restrict__ g2g, const float* __restrict__ g3g,
           float* __restrict__ outg) {
    const int lane = threadIdx.x;
    const bool is0 = (lane == 0);
    const bool is63 = (lane == 63);
    const size_t pb = (size_t)blockIdx.x * 16384;  // plane base in float4 units
    const float4* px = reinterpret_cast<const float4*>(xg) + pb;
    const float4* p1 = reinterpret_cast<const float4*>(g1g) + pb;
    const float4* p2 = reinterpret_cast<const float4*>(g2g) + pb;
    const float4* p3 = reinterpret_cast<const float4*>(g3g) + pb;
    float4* po = reinterpret_cast<float4*>(outg) + pb;

    __shared__ float lds[16384];  // 64 KB exactly

    const int lrow = lane >> 1;        // row within 32-row load block
    const int lchk = lane & 1;         // f4 chunk within 8-col group
    const int wkey = (lane >> 2) & 7;  // write-side swizzle key ((r>>1)&7)
    const int rkey = (lane >> 1) & 7;  // read-side swizzle key  ((r>>1)&7)

    float4 LA[8], LB[8], LC[8], LD[8];  // staging, 128 VGPRs
    float RS0[16], RS1[16];             // col regs [a*4+s], ping-pong
    float4 oa0, oa1, oa2, oa3;          // out accum, cols 0-3 of group
    float4 ob0, ob1, ob2, ob3;          // out accum, cols 4-7
    float h0 = 0.f, h1 = 0.f, h2 = 0.f, h3 = 0.f;  // stripes' running h

    // ---- load one array's 8-col group G into REG (8 x 1KB-contig instrs) ----
#define LOADA(REG, PTR, G)                                                    \
    do {                                                                      \
        const int go_ = (G) * 2 + lchk;                                       \
        _Pragma("unroll") for (int j_ = 0; j_ < 8; ++j_) {                    \
            REG[j_] = PTR[(32 * j_ + lrow) * 64 + go_];                       \
        }                                                                     \
    } while (0)

    // ---- ds_write array AI's group from REG into buffer base BB ----
#define WRITEA(AI, REG, BB)                                                   \
    do {                                                                      \
        const int c0_ = (4 * lchk + 0) ^ wkey;                                \
        const int c1_ = (4 * lchk + 1) ^ wkey;                                \
        const int c2_ = (4 * lchk + 2) ^ wkey;                                \
        const int c3_ = (4 * lchk + 3) ^ wkey;                                \
        _Pragma("unroll") for (int j_ = 0; j_ < 8; ++j_) {                    \
            const int ba_ = (BB) + (AI) * 2048 + (32 * j_ + lrow) * 8;        \
            lds[ba_ + c0_] = REG[j_].x;                                       \
            lds[ba_ + c1_] = REG[j_].y;                                       \
            lds[ba_ + c2_] = REG[j_].z;                                       \
            lds[ba_ + c3_] = REG[j_].w;                                       \
        }                                                                     \
    } while (0)

    // ---- read local col C (0..7) of buffer BB into RS[a*4+s] ----
#define READCOL(C, BB, RS)                                                    \
    do {                                                                      \
        const int cc_ = (C) ^ rkey;                                           \
        _Pragma("unroll") for (int a_ = 0; a_ < 4; ++a_) {                    \
            _Pragma("unroll") for (int s_ = 0; s_ < 4; ++s_) {                \
                RS[a_ * 4 + s_] =                                             \
                    lds[(BB) + a_ * 2048 + (64 * s_ + lane) * 8 + cc_];       \
            }                                                                 \
        }                                                                     \
    } while (0)

    // ---- one row's normalize + recurrence ----
#define ROWX(RS, S, HU, HC, HD, NV)                                           \
    do {                                                                      \
        const float X_ = RS[S];                                               \
        float A1_ = RS[4 + S], A2_ = RS[8 + S], A3_ = RS[12 + S];             \
        const float sa_ = fabsf(A1_) + fabsf(A2_) + fabsf(A3_);               \
        const float inv_ = (sa_ >= 1.0f) ? __builtin_amdgcn_rcpf(sa_) : 1.0f; \
        A1_ *= inv_; A2_ *= inv_; A3_ *= inv_;                                \
        const float dd_ = (1.0f - A1_ - A2_ - A3_) * X_;                      \
        NV = fmaf(A1_, HU, fmaf(A2_, HC, fmaf(A3_, HD, dd_)));                \
    } while (0)

    // ---- one column: shfl exchange + 4 stripes; accumulate out[H][K] ----
#define COMPUTE(RS, H, K)                                                     \
    do {                                                                      \
        const float u0_ = __shfl_up(h0, 1), u1_ = __shfl_up(h1, 1);           \
        const float u2_ = __shfl_up(h2, 1), u3_ = __shfl_up(h3, 1);           \
        const float d0_ = __shfl_down(h0, 1), d1_ = __shfl_down(h1, 1);       \
        const float d2_ = __shfl_down(h2, 1), d3_ = __shfl_down(h3, 1);       \
        const float b1_ = __shfl(h0, 63), b2_ = __shfl(h1, 63);               \
        const float b3_ = __shfl(h2, 63);                                     \
        const float e0_ = __shfl(h1, 0), e1_ = __shfl(h2, 0);                 \
        const float e2_ = __shfl(h3, 0);                                      \
        const float up0 = is0 ? 0.0f : u0_;                                   \
        const float up1 = is0 ? b1_ : u1_;                                    \
        const float up2 = is0 ? b2_ : u2_;                                    \
        const float up3 = is0 ? b3_ : u3_;                                    \
        const float dn0 = is63 ? e0_ : d0_;                                   \
        const float dn1 = is63 ? e1_ : d1_;                                   \
        const float dn2 = is63 ? e2_ : d2_;                                   \
        const float dn3 = is63 ? 0.0f : d3_;                                  \
        float n0_, n1_, n2_, n3_;                                             \
        ROWX(RS, 0, up0, h0, dn0, n0_);                                       \
        ROWX(RS, 1, up1, h1, dn1, n1_);                                       \
        ROWX(RS, 2, up2, h2, dn2, n2_);                                       \
        ROWX(RS, 3, up3, h3, dn3, n3_);                                       \
        h0 = n0_; h1 = n1_; h2 = n2_; h3 = n3_;                               \
        SETEL(o##H##0, K, n0_);                                               \
        SETEL(o##H##1, K, n1_);                                               \
        SETEL(o##H##2, K, n2_);                                               \
        SETEL(o##H##3, K, n3_);                                               \
    } while (0)

    // ---- store group G: per stripe, 2 adjacent f4 (32B burst) ----
#define STOREG(G)                                                             \
    do {                                                                      \
        po[(lane) * 64 + (G) * 2 + 0] = oa0;                                  \
        po[(lane) * 64 + (G) * 2 + 1] = ob0;                                  \
        po[(64 + lane) * 64 + (G) * 2 + 0] = oa1;                             \
        po[(64 + lane) * 64 + (G) * 2 + 1] = ob1;                             \
        po[(128 + lane) * 64 + (G) * 2 + 0] = oa2;                            \
        po[(128 + lane) * 64 + (G) * 2 + 1] = ob2;                            \
        po[(192 + lane) * 64 + (G) * 2 + 0] = oa3;                            \
        po[(192 + lane) * 64 + (G) * 2 + 1] = ob3;                            \
    } while (0)

    // ---- prologue: group 0 -> buf0; group 1 -> L regs ----
    LOADA(LA, px, 0); LOADA(LB, p1, 0); LOADA(LC, p2, 0); LOADA(LD, p3, 0);
    WRITEA(0, LA, 0); WRITEA(1, LB, 0); WRITEA(2, LC, 0); WRITEA(3, LD, 0);
    LOADA(LA, px, 1); LOADA(LB, p1, 1); LOADA(LC, p2, 1); LOADA(LD, p3, 1);
    FENCE();
    READCOL(0, 0, RS0);

    // ---- main loop: 32 groups of 8 cols, no barriers anywhere ----
#pragma unroll 1
    for (int g = 0; g < 32; ++g) {
        const int bcur = (g & 1) << 13;  // 0 / 8192 dwords
        const int bnxt = bcur ^ 8192;
        const bool wr = (g < 31);  // L holds group g+1 -> write it
        const bool ld = (g < 30);  // refill L with group g+2

        COMPUTE(RS0, a, 0); READCOL(1, bcur, RS1); if (wr) WRITEA(0, LA, bnxt); FENCE();
        COMPUTE(RS1, a, 1); READCOL(2, bcur, RS0); if (wr) WRITEA(1, LB, bnxt); if (ld) LOADA(LA, px, g + 2); FENCE();
        COMPUTE(RS0, a, 2); READCOL(3, bcur, RS1); if (wr) WRITEA(2, LC, bnxt); if (ld) LOADA(LB, p1, g + 2); FENCE();
        COMPUTE(RS1, a, 3); READCOL(4, bcur, RS0); if (wr) WRITEA(3, LD, bnxt); if (ld) LOADA(LC, p2, g + 2); FENCE();
        COMPUTE(RS0, b, 0); READCOL(5, bcur, RS1); if (ld) LOADA(LD, p3, g + 2); FENCE();
        COMPUTE(RS1, b, 1); READCOL(6, bcur, RS0); FENCE();
        COMPUTE(RS0, b, 2); READCOL(7, bcur, RS1); FENCE();
        COMPUTE(RS1, b, 3);
        if (wr) READCOL(0, bnxt, RS0);
        STOREG(g);
        FENCE();
    }

#undef STOREG
#undef COMPUTE
#undef ROWX
#undef READCOL
#undef WRITEA
#undef LOADA
}

extern "C" void kernel_launch(void* const* d_in, const int* in_sizes, int n_in,
                              void* d_out, int out_size, void* d_ws, size_t ws_size,
                              hipStream_t stream) {
    const float* x  = (const float*)d_in[0];
    const float* G1 = (const float*)d_in[1];
    const float* G2 = (const float*)d_in[2];
    const float* G3 = (const float*)d_in[3];
    float* out = (float*)d_out;

    const int nplanes = in_sizes[0] / (256 * 256);  // B*C = 256
    spn_wave_x<<<dim3(nplanes), dim3(64), 0, stream>>>(x, G1, G2, G3, out);
}